// Round 6
// baseline (153.058 us; speedup 1.0000x reference)
//
#include <hip/hip_runtime.h>

#define DROWS 4096
#define NCOLS 8192

// ---- ordered-uint encoding so unsigned atomicMin/Max == float min/max ----
__device__ __forceinline__ unsigned encf(float f) {
    unsigned u = __float_as_uint(f);
    return (u & 0x80000000u) ? ~u : (u | 0x80000000u);
}
__device__ __forceinline__ float decf(unsigned u) {
    unsigned v = (u & 0x80000000u) ? (u ^ 0x80000000u) : ~u;
    return __uint_as_float(v);
}

__global__ __launch_bounds__(256) void init_minmax(unsigned* __restrict__ mine,
                                                   unsigned* __restrict__ maxe) {
    int i = blockIdx.x * 256 + threadIdx.x;
    mine[i] = 0xFFFFFFFFu;  // encoded +inf-ish (largest key)
    maxe[i] = 0u;           // smallest key
}

// Per-column min/max. grid = (8, 64): blockIdx.x tiles 1024 columns (256 thr * 4),
// blockIdx.y tiles 64 rows. Coalesced float4 loads; 8 atomics per thread at the end.
__global__ __launch_bounds__(256) void colminmax(const float* __restrict__ x,
                                                 unsigned* __restrict__ mine,
                                                 unsigned* __restrict__ maxe) {
    int c = blockIdx.x * 1024 + threadIdx.x * 4;
    int r0 = blockIdx.y * 64;
    const float* p = x + (size_t)r0 * NCOLS + c;

    float4 mn = *(const float4*)p;
    float4 mx = mn;
#pragma unroll 8
    for (int i = 1; i < 64; ++i) {
        float4 v = *(const float4*)(p + (size_t)i * NCOLS);
        mn.x = fminf(mn.x, v.x); mn.y = fminf(mn.y, v.y);
        mn.z = fminf(mn.z, v.z); mn.w = fminf(mn.w, v.w);
        mx.x = fmaxf(mx.x, v.x); mx.y = fmaxf(mx.y, v.y);
        mx.z = fmaxf(mx.z, v.z); mx.w = fmaxf(mx.w, v.w);
    }
    atomicMin(&mine[c + 0], encf(mn.x));
    atomicMin(&mine[c + 1], encf(mn.y));
    atomicMin(&mine[c + 2], encf(mn.z));
    atomicMin(&mine[c + 3], encf(mn.w));
    atomicMax(&maxe[c + 0], encf(mx.x));
    atomicMax(&maxe[c + 1], encf(mx.y));
    atomicMax(&maxe[c + 2], encf(mx.z));
    atomicMax(&maxe[c + 3], encf(mx.w));
}

// Decode min/max; write fmin, and overwrite mine<-safe_range, maxe<-1/safe_range
// (same index read-then-write by the same thread: race-free).
__global__ __launch_bounds__(256) void finalize_minmax(unsigned* __restrict__ mine,
                                                       unsigned* __restrict__ maxe,
                                                       float* __restrict__ fmin) {
    int i = blockIdx.x * 256 + threadIdx.x;
    float mn = decf(mine[i]);
    float mx = decf(maxe[i]);
    float r = mx - mn;
    float sr = (r == 0.0f) ? 1.0f : r;  // sklearn _handle_zeros_in_scale
    fmin[i] = mn;
    ((float*)mine)[i] = sr;
    ((float*)maxe)[i] = 1.0f / sr;  // correctly-rounded reciprocal
}

// Wave-per-row: each 64-lane wave owns a full 8192-elem row in registers
// (32 x float4 per lane). Row sums are pure shfl_xor butterflies -> no
// __syncthreads, no LDS, no inter-wave coupling. 4 waves (rows) per block.
__global__ __launch_bounds__(256) void rowiter(const float* __restrict__ x,
                                               const float* __restrict__ fmin,
                                               const float* __restrict__ fsr,
                                               const float* __restrict__ finv,
                                               float* __restrict__ out) {
    int wave = threadIdx.x >> 6;
    int lane = threadIdx.x & 63;
    int row = blockIdx.x * 4 + wave;
    const float* xr = x + (size_t)row * NCOLS;
    float* outr = out + (size_t)row * NCOLS;

    float4 a[32];
    float psum = 0.0f;
#pragma unroll
    for (int k = 0; k < 32; ++k) {
        int c = k * 256 + lane * 4;
        float4 v = *(const float4*)(xr + c);
        float4 mn = *(const float4*)(fmin + c);
        float4 iv = *(const float4*)(finv + c);
        float4 t;
        t.x = (v.x - mn.x) * iv.x;
        t.y = (v.y - mn.y) * iv.y;
        t.z = (v.z - mn.z) * iv.z;
        t.w = (v.w - mn.w) * iv.w;
        a[k] = t;
        psum += (t.x + t.y) + (t.z + t.w);
    }
    float sum = psum;
#pragma unroll
    for (int m = 32; m; m >>= 1) sum += __shfl_xor(sum, m, 64);

#pragma unroll
    for (int it = 0; it < 10; ++it) {
        float mean = sum * (1.0f / 8192.0f);  // exact pow-2: identical to /8192
        float add = (it == 0) ? 0.001f : 0.0f;
        psum = 0.0f;
#pragma unroll
        for (int k = 0; k < 32; ++k) {
            float4 t = a[k];
            t.x = t.x * (1.0f - (t.x - mean)) + add;
            t.y = t.y * (1.0f - (t.y - mean)) + add;
            t.z = t.z * (1.0f - (t.z - mean)) + add;
            t.w = t.w * (1.0f - (t.w - mean)) + add;
            a[k] = t;
            psum += (t.x + t.y) + (t.z + t.w);
        }
        if (it < 9) {
            sum = psum;
#pragma unroll
            for (int m = 32; m; m >>= 1) sum += __shfl_xor(sum, m, 64);
        }
    }

#pragma unroll
    for (int k = 0; k < 32; ++k) {
        int c = k * 256 + lane * 4;
        float4 mn = *(const float4*)(fmin + c);
        float4 sr = *(const float4*)(fsr + c);
        float4 t = a[k];
        float4 o;
        o.x = fmaf(t.x, sr.x, mn.x);
        o.y = fmaf(t.y, sr.y, mn.y);
        o.z = fmaf(t.z, sr.z, mn.z);
        o.w = fmaf(t.w, sr.w, mn.w);
        *(float4*)(outr + c) = o;
    }
}

extern "C" void kernel_launch(void* const* d_in, const int* in_sizes, int n_in,
                              void* d_out, int out_size, void* d_ws, size_t ws_size,
                              hipStream_t stream) {
    const float* x = (const float*)d_in[0];
    float* out = (float*)d_out;

    // ws layout: mine[8192] u32 (-> fsr f32) | maxe[8192] u32 (-> finv f32) |
    //            fmin[8192] f32  = 96 KiB total
    unsigned* mine = (unsigned*)d_ws;
    unsigned* maxe = mine + NCOLS;
    float* fmin = (float*)(maxe + NCOLS);

    init_minmax<<<NCOLS / 256, 256, 0, stream>>>(mine, maxe);
    colminmax<<<dim3(NCOLS / 1024, DROWS / 64), 256, 0, stream>>>(x, mine, maxe);
    finalize_minmax<<<NCOLS / 256, 256, 0, stream>>>(mine, maxe, fmin);
    rowiter<<<DROWS / 4, 256, 0, stream>>>(x, fmin, (const float*)mine,
                                           (const float*)maxe, out);
}

// Round 7
// 95.800 us; speedup vs baseline: 1.5977x; 1.5977x over previous
//
#include <hip/hip_runtime.h>

#define DROWS 4096
#define NCOLS 8192

// ---- ordered-uint encoding so unsigned atomicMin/Max == float min/max ----
__device__ __forceinline__ unsigned encf(float f) {
    unsigned u = __float_as_uint(f);
    return (u & 0x80000000u) ? ~u : (u | 0x80000000u);
}
__device__ __forceinline__ float decf(unsigned u) {
    unsigned v = (u & 0x80000000u) ? (u ^ 0x80000000u) : ~u;
    return __uint_as_float(v);
}

__global__ __launch_bounds__(256) void init_minmax(unsigned* __restrict__ mine,
                                                   unsigned* __restrict__ maxe) {
    int i = blockIdx.x * 256 + threadIdx.x;
    mine[i] = 0xFFFFFFFFu;  // encoded +inf-ish (largest key)
    maxe[i] = 0u;           // smallest key
}

// Per-column min/max. grid = (8, 64): blockIdx.x tiles 1024 columns (256 thr * 4),
// blockIdx.y tiles 64 rows. Coalesced float4 loads; 8 atomics per thread at the end.
__global__ __launch_bounds__(256) void colminmax(const float* __restrict__ x,
                                                 unsigned* __restrict__ mine,
                                                 unsigned* __restrict__ maxe) {
    int c = blockIdx.x * 1024 + threadIdx.x * 4;
    int r0 = blockIdx.y * 64;
    const float* p = x + (size_t)r0 * NCOLS + c;

    float4 mn = *(const float4*)p;
    float4 mx = mn;
#pragma unroll 8
    for (int i = 1; i < 64; ++i) {
        float4 v = *(const float4*)(p + (size_t)i * NCOLS);
        mn.x = fminf(mn.x, v.x); mn.y = fminf(mn.y, v.y);
        mn.z = fminf(mn.z, v.z); mn.w = fminf(mn.w, v.w);
        mx.x = fmaxf(mx.x, v.x); mx.y = fmaxf(mx.y, v.y);
        mx.z = fmaxf(mx.z, v.z); mx.w = fmaxf(mx.w, v.w);
    }
    atomicMin(&mine[c + 0], encf(mn.x));
    atomicMin(&mine[c + 1], encf(mn.y));
    atomicMin(&mine[c + 2], encf(mn.z));
    atomicMin(&mine[c + 3], encf(mn.w));
    atomicMax(&maxe[c + 0], encf(mx.x));
    atomicMax(&maxe[c + 1], encf(mx.y));
    atomicMax(&maxe[c + 2], encf(mx.z));
    atomicMax(&maxe[c + 3], encf(mx.w));
}

// Decode min/max; write fmin, and overwrite mine<-safe_range, maxe<-1/safe_range
// (same index read-then-write by the same thread: race-free).
__global__ __launch_bounds__(256) void finalize_minmax(unsigned* __restrict__ mine,
                                                       unsigned* __restrict__ maxe,
                                                       float* __restrict__ fmin) {
    int i = blockIdx.x * 256 + threadIdx.x;
    float mn = decf(mine[i]);
    float mx = decf(maxe[i]);
    float r = mx - mn;
    float sr = (r == 0.0f) ? 1.0f : r;  // sklearn _handle_zeros_in_scale
    fmin[i] = mn;
    ((float*)mine)[i] = sr;
    ((float*)maxe)[i] = 1.0f / sr;  // correctly-rounded reciprocal
}

// Reduce two block sums with ONE barrier pair (red[0..3]=sum0, red[4..7]=sum1).
__device__ __forceinline__ void block_sum2(float& v0, float& v1, float* red) {
#pragma unroll
    for (int m = 32; m; m >>= 1) {
        v0 += __shfl_xor(v0, m, 64);
        v1 += __shfl_xor(v1, m, 64);
    }
    int wid = threadIdx.x >> 6;
    int lane = threadIdx.x & 63;
    __syncthreads();  // protect red[] from previous round's readers
    if (lane == 0) { red[wid] = v0; red[4 + wid] = v1; }
    __syncthreads();
    v0 = red[0] + red[1] + red[2] + red[3];
    v1 = red[4] + red[5] + red[6] + red[7];
}

// Two rows per 256-thread block. Each row: 8 x float4 per thread in registers
// (64 VGPRs of data total). Both rows share one barrier pair per iteration;
// the two independent mean/update chains give 2x ILP.
__global__ __launch_bounds__(256) void rowiter(const float* __restrict__ x,
                                               const float* __restrict__ fmin,
                                               const float* __restrict__ fsr,
                                               const float* __restrict__ finv,
                                               float* __restrict__ out) {
    int t = threadIdx.x;
    size_t r0 = (size_t)blockIdx.x * 2;
    const float* xr0 = x + r0 * NCOLS;
    const float* xr1 = xr0 + NCOLS;
    float* outr0 = out + r0 * NCOLS;
    float* outr1 = outr0 + NCOLS;

    __shared__ float red[8];

    float4 a0[8], a1[8];
    float ps0 = 0.0f, ps1 = 0.0f;
#pragma unroll
    for (int k = 0; k < 8; ++k) {
        int c = k * 1024 + t * 4;
        float4 mn = *(const float4*)(fmin + c);
        float4 iv = *(const float4*)(finv + c);
        float4 v0 = *(const float4*)(xr0 + c);
        float4 v1 = *(const float4*)(xr1 + c);
        float4 u0, u1;
        u0.x = (v0.x - mn.x) * iv.x;  u1.x = (v1.x - mn.x) * iv.x;
        u0.y = (v0.y - mn.y) * iv.y;  u1.y = (v1.y - mn.y) * iv.y;
        u0.z = (v0.z - mn.z) * iv.z;  u1.z = (v1.z - mn.z) * iv.z;
        u0.w = (v0.w - mn.w) * iv.w;  u1.w = (v1.w - mn.w) * iv.w;
        a0[k] = u0; a1[k] = u1;
        ps0 += (u0.x + u0.y) + (u0.z + u0.w);
        ps1 += (u1.x + u1.y) + (u1.z + u1.w);
    }
    block_sum2(ps0, ps1, red);
    float sum0 = ps0, sum1 = ps1;

#pragma unroll
    for (int it = 0; it < 10; ++it) {
        float mean0 = sum0 * (1.0f / 8192.0f);  // exact pow-2: identical to /8192
        float mean1 = sum1 * (1.0f / 8192.0f);
        float add = (it == 0) ? 0.001f : 0.0f;
        ps0 = 0.0f; ps1 = 0.0f;
#pragma unroll
        for (int k = 0; k < 8; ++k) {
            float4 u0 = a0[k], u1 = a1[k];
            u0.x = u0.x * (1.0f - (u0.x - mean0)) + add;
            u0.y = u0.y * (1.0f - (u0.y - mean0)) + add;
            u0.z = u0.z * (1.0f - (u0.z - mean0)) + add;
            u0.w = u0.w * (1.0f - (u0.w - mean0)) + add;
            u1.x = u1.x * (1.0f - (u1.x - mean1)) + add;
            u1.y = u1.y * (1.0f - (u1.y - mean1)) + add;
            u1.z = u1.z * (1.0f - (u1.z - mean1)) + add;
            u1.w = u1.w * (1.0f - (u1.w - mean1)) + add;
            a0[k] = u0; a1[k] = u1;
            ps0 += (u0.x + u0.y) + (u0.z + u0.w);
            ps1 += (u1.x + u1.y) + (u1.z + u1.w);
        }
        if (it < 9) {
            block_sum2(ps0, ps1, red);
            sum0 = ps0; sum1 = ps1;
        }
    }

#pragma unroll
    for (int k = 0; k < 8; ++k) {
        int c = k * 1024 + t * 4;
        float4 mn = *(const float4*)(fmin + c);
        float4 sr = *(const float4*)(fsr + c);
        float4 u0 = a0[k], u1 = a1[k];
        float4 o0, o1;
        o0.x = fmaf(u0.x, sr.x, mn.x);  o1.x = fmaf(u1.x, sr.x, mn.x);
        o0.y = fmaf(u0.y, sr.y, mn.y);  o1.y = fmaf(u1.y, sr.y, mn.y);
        o0.z = fmaf(u0.z, sr.z, mn.z);  o1.z = fmaf(u1.z, sr.z, mn.z);
        o0.w = fmaf(u0.w, sr.w, mn.w);  o1.w = fmaf(u1.w, sr.w, mn.w);
        *(float4*)(outr0 + c) = o0;
        *(float4*)(outr1 + c) = o1;
    }
}

extern "C" void kernel_launch(void* const* d_in, const int* in_sizes, int n_in,
                              void* d_out, int out_size, void* d_ws, size_t ws_size,
                              hipStream_t stream) {
    const float* x = (const float*)d_in[0];
    float* out = (float*)d_out;

    // ws layout: mine[8192] u32 (-> fsr f32) | maxe[8192] u32 (-> finv f32) |
    //            fmin[8192] f32  = 96 KiB total
    unsigned* mine = (unsigned*)d_ws;
    unsigned* maxe = mine + NCOLS;
    float* fmin = (float*)(maxe + NCOLS);

    init_minmax<<<NCOLS / 256, 256, 0, stream>>>(mine, maxe);
    colminmax<<<dim3(NCOLS / 1024, DROWS / 64), 256, 0, stream>>>(x, mine, maxe);
    finalize_minmax<<<NCOLS / 256, 256, 0, stream>>>(mine, maxe, fmin);
    rowiter<<<DROWS / 2, 256, 0, stream>>>(x, fmin, (const float*)mine,
                                           (const float*)maxe, out);
}

// Round 8
// 89.706 us; speedup vs baseline: 1.7062x; 1.0679x over previous
//
#include <hip/hip_runtime.h>

#define DROWS 4096
#define NCOLS 8192

// ---- ordered-uint encoding so unsigned atomicMin/Max == float min/max ----
// init via memset: mine=0xFFFFFFFF (max key), maxe=0x00000000 (min key)
__device__ __forceinline__ unsigned encf(float f) {
    unsigned u = __float_as_uint(f);
    return (u & 0x80000000u) ? ~u : (u | 0x80000000u);
}
__device__ __forceinline__ float decf(unsigned u) {
    unsigned v = (u & 0x80000000u) ? (u ^ 0x80000000u) : ~u;
    return __uint_as_float(v);
}

// Per-column min/max. grid = (8, 64): blockIdx.x tiles 1024 columns (256 thr * 4),
// blockIdx.y tiles 64 rows. Coalesced float4 loads; 8 atomics per thread at the end.
__global__ __launch_bounds__(256) void colminmax(const float* __restrict__ x,
                                                 unsigned* __restrict__ mine,
                                                 unsigned* __restrict__ maxe) {
    int c = blockIdx.x * 1024 + threadIdx.x * 4;
    int r0 = blockIdx.y * 64;
    const float* p = x + (size_t)r0 * NCOLS + c;

    float4 mn = *(const float4*)p;
    float4 mx = mn;
#pragma unroll 8
    for (int i = 1; i < 64; ++i) {
        float4 v = *(const float4*)(p + (size_t)i * NCOLS);
        mn.x = fminf(mn.x, v.x); mn.y = fminf(mn.y, v.y);
        mn.z = fminf(mn.z, v.z); mn.w = fminf(mn.w, v.w);
        mx.x = fmaxf(mx.x, v.x); mx.y = fmaxf(mx.y, v.y);
        mx.z = fmaxf(mx.z, v.z); mx.w = fmaxf(mx.w, v.w);
    }
    atomicMin(&mine[c + 0], encf(mn.x));
    atomicMin(&mine[c + 1], encf(mn.y));
    atomicMin(&mine[c + 2], encf(mn.z));
    atomicMin(&mine[c + 3], encf(mn.w));
    atomicMax(&maxe[c + 0], encf(mx.x));
    atomicMax(&maxe[c + 1], encf(mx.y));
    atomicMax(&maxe[c + 2], encf(mx.z));
    atomicMax(&maxe[c + 3], encf(mx.w));
}

// Decode min/max; write fmin, and overwrite mine<-safe_range, maxe<-1/safe_range
// (same index read-then-write by the same thread: race-free).
__global__ __launch_bounds__(256) void finalize_minmax(unsigned* __restrict__ mine,
                                                       unsigned* __restrict__ maxe,
                                                       float* __restrict__ fmin) {
    int i = blockIdx.x * 256 + threadIdx.x;
    float mn = decf(mine[i]);
    float mx = decf(maxe[i]);
    float r = mx - mn;
    float sr = (r == 0.0f) ? 1.0f : r;  // sklearn _handle_zeros_in_scale
    fmin[i] = mn;
    ((float*)mine)[i] = sr;
    ((float*)maxe)[i] = 1.0f / sr;  // correctly-rounded reciprocal
}

__device__ __forceinline__ float block_sum(float v, float* red) {
#pragma unroll
    for (int m = 32; m; m >>= 1) v += __shfl_xor(v, m, 64);
    int wid = threadIdx.x >> 6;
    int lane = threadIdx.x & 63;
    __syncthreads();             // protect red[] from previous round's readers
    if (lane == 0) red[wid] = v;
    __syncthreads();
    return red[0] + red[1] + red[2] + red[3];
}

// One block per row; 8 x float4 per thread in registers (32 VGPRs of data).
// __launch_bounds__(256, 6): cap VGPR at 85 -> 6 waves/SIMD (6 blocks/CU) so
// load/compute/store phases of different resident blocks overlap.
__global__ __launch_bounds__(256, 6) void rowiter(const float* __restrict__ x,
                                                  const float* __restrict__ fmin,
                                                  const float* __restrict__ fsr,
                                                  const float* __restrict__ finv,
                                                  float* __restrict__ out) {
    int row = blockIdx.x;
    int t = threadIdx.x;
    const float* xr = x + (size_t)row * NCOLS;
    float* outr = out + (size_t)row * NCOLS;

    __shared__ float red[4];

    float4 a[8];
    float psum = 0.0f;
#pragma unroll
    for (int k = 0; k < 8; ++k) {
        int c = k * 1024 + t * 4;
        float4 v = *(const float4*)(xr + c);
        float4 mn = *(const float4*)(fmin + c);
        float4 iv = *(const float4*)(finv + c);
        float4 u;
        u.x = (v.x - mn.x) * iv.x;
        u.y = (v.y - mn.y) * iv.y;
        u.z = (v.z - mn.z) * iv.z;
        u.w = (v.w - mn.w) * iv.w;
        a[k] = u;
        psum += (u.x + u.y) + (u.z + u.w);
    }
    float sum = block_sum(psum, red);

#pragma unroll
    for (int it = 0; it < 10; ++it) {
        float mean = sum * (1.0f / 8192.0f);  // exact pow-2: identical to /8192
        float add = (it == 0) ? 0.001f : 0.0f;
        psum = 0.0f;
#pragma unroll
        for (int k = 0; k < 8; ++k) {
            float4 u = a[k];
            u.x = u.x * (1.0f - (u.x - mean)) + add;
            u.y = u.y * (1.0f - (u.y - mean)) + add;
            u.z = u.z * (1.0f - (u.z - mean)) + add;
            u.w = u.w * (1.0f - (u.w - mean)) + add;
            a[k] = u;
            psum += (u.x + u.y) + (u.z + u.w);
        }
        if (it < 9) sum = block_sum(psum, red);  // uniform condition: barrier-safe
    }

#pragma unroll
    for (int k = 0; k < 8; ++k) {
        int c = k * 1024 + t * 4;
        float4 mn = *(const float4*)(fmin + c);
        float4 sr = *(const float4*)(fsr + c);
        float4 u = a[k];
        float4 o;
        o.x = fmaf(u.x, sr.x, mn.x);
        o.y = fmaf(u.y, sr.y, mn.y);
        o.z = fmaf(u.z, sr.z, mn.z);
        o.w = fmaf(u.w, sr.w, mn.w);
        *(float4*)(outr + c) = o;
    }
}

extern "C" void kernel_launch(void* const* d_in, const int* in_sizes, int n_in,
                              void* d_out, int out_size, void* d_ws, size_t ws_size,
                              hipStream_t stream) {
    const float* x = (const float*)d_in[0];
    float* out = (float*)d_out;

    // ws layout: mine[8192] u32 (-> fsr f32) | maxe[8192] u32 (-> finv f32) |
    //            fmin[8192] f32  = 96 KiB total
    unsigned* mine = (unsigned*)d_ws;
    unsigned* maxe = mine + NCOLS;
    float* fmin = (float*)(maxe + NCOLS);

    hipMemsetAsync(mine, 0xFF, NCOLS * sizeof(unsigned), stream);  // encoded-min identity
    hipMemsetAsync(maxe, 0x00, NCOLS * sizeof(unsigned), stream);  // encoded-max identity
    colminmax<<<dim3(NCOLS / 1024, DROWS / 64), 256, 0, stream>>>(x, mine, maxe);
    finalize_minmax<<<NCOLS / 256, 256, 0, stream>>>(mine, maxe, fmin);
    rowiter<<<DROWS, 256, 0, stream>>>(x, fmin, (const float*)mine,
                                       (const float*)maxe, out);
}

// Round 9
// 88.235 us; speedup vs baseline: 1.7347x; 1.0167x over previous
//
#include <hip/hip_runtime.h>

#define DROWS 4096
#define NCOLS 8192

// ---- ordered-uint encoding so unsigned atomicMin/Max == float min/max ----
// init via memset: mine=0xFFFFFFFF (max key), maxe=0x00000000 (min key)
__device__ __forceinline__ unsigned encf(float f) {
    unsigned u = __float_as_uint(f);
    return (u & 0x80000000u) ? ~u : (u | 0x80000000u);
}
__device__ __forceinline__ float decf(unsigned u) {
    unsigned v = (u & 0x80000000u) ? (u ^ 0x80000000u) : ~u;
    return __uint_as_float(v);
}

// Per-column min/max. grid = (8, 64): blockIdx.x tiles 1024 columns (256 thr * 4),
// blockIdx.y tiles 64 rows. Coalesced float4 loads; 8 atomics per thread at the end.
// Regular (caching) loads on purpose: this pass warms L3 with x for rowiter.
__global__ __launch_bounds__(256) void colminmax(const float* __restrict__ x,
                                                 unsigned* __restrict__ mine,
                                                 unsigned* __restrict__ maxe) {
    int c = blockIdx.x * 1024 + threadIdx.x * 4;
    int r0 = blockIdx.y * 64;
    const float* p = x + (size_t)r0 * NCOLS + c;

    float4 mn = *(const float4*)p;
    float4 mx = mn;
#pragma unroll 8
    for (int i = 1; i < 64; ++i) {
        float4 v = *(const float4*)(p + (size_t)i * NCOLS);
        mn.x = fminf(mn.x, v.x); mn.y = fminf(mn.y, v.y);
        mn.z = fminf(mn.z, v.z); mn.w = fminf(mn.w, v.w);
        mx.x = fmaxf(mx.x, v.x); mx.y = fmaxf(mx.y, v.y);
        mx.z = fmaxf(mx.z, v.z); mx.w = fmaxf(mx.w, v.w);
    }
    atomicMin(&mine[c + 0], encf(mn.x));
    atomicMin(&mine[c + 1], encf(mn.y));
    atomicMin(&mine[c + 2], encf(mn.z));
    atomicMin(&mine[c + 3], encf(mn.w));
    atomicMax(&maxe[c + 0], encf(mx.x));
    atomicMax(&maxe[c + 1], encf(mx.y));
    atomicMax(&maxe[c + 2], encf(mx.z));
    atomicMax(&maxe[c + 3], encf(mx.w));
}

// Decode min/max; write fmin, and overwrite mine<-safe_range, maxe<-1/safe_range
// (same index read-then-write by the same thread: race-free).
__global__ __launch_bounds__(256) void finalize_minmax(unsigned* __restrict__ mine,
                                                       unsigned* __restrict__ maxe,
                                                       float* __restrict__ fmin) {
    int i = blockIdx.x * 256 + threadIdx.x;
    float mn = decf(mine[i]);
    float mx = decf(maxe[i]);
    float r = mx - mn;
    float sr = (r == 0.0f) ? 1.0f : r;  // sklearn _handle_zeros_in_scale
    fmin[i] = mn;
    ((float*)mine)[i] = sr;
    ((float*)maxe)[i] = 1.0f / sr;  // correctly-rounded reciprocal
}

// One-barrier block sum: double-buffered slots. Call c writes red[(c&1)*4 ..];
// the next write to that slot (call c+2) is separated from call c's readers by
// call c+1's barrier -> race-free with a single __syncthreads per call.
__device__ __forceinline__ float block_sum(float v, float* red, int slot) {
#pragma unroll
    for (int m = 32; m; m >>= 1) v += __shfl_xor(v, m, 64);
    int wid = threadIdx.x >> 6;
    int lane = threadIdx.x & 63;
    if (lane == 0) red[slot * 4 + wid] = v;
    __syncthreads();
    float* r = red + slot * 4;
    return r[0] + r[1] + r[2] + r[3];
}

// One block per row; 8 x float4 per thread in registers (32 VGPRs of data).
// __launch_bounds__(256, 6): 6 blocks/CU so load/compute/store phases of
// different resident blocks overlap. Output uses NON-TEMPORAL stores so the
// write stream doesn't evict the L3-resident x (warmed by colminmax).
__global__ __launch_bounds__(256, 6) void rowiter(const float* __restrict__ x,
                                                  const float* __restrict__ fmin,
                                                  const float* __restrict__ fsr,
                                                  const float* __restrict__ finv,
                                                  float* __restrict__ out) {
    int row = blockIdx.x;
    int t = threadIdx.x;
    const float* xr = x + (size_t)row * NCOLS;
    float* outr = out + (size_t)row * NCOLS;

    __shared__ float red[8];

    float4 a[8];
    float psum = 0.0f;
#pragma unroll
    for (int k = 0; k < 8; ++k) {
        int c = k * 1024 + t * 4;
        float4 v = *(const float4*)(xr + c);
        float4 mn = *(const float4*)(fmin + c);
        float4 iv = *(const float4*)(finv + c);
        float4 u;
        u.x = (v.x - mn.x) * iv.x;
        u.y = (v.y - mn.y) * iv.y;
        u.z = (v.z - mn.z) * iv.z;
        u.w = (v.w - mn.w) * iv.w;
        a[k] = u;
        psum += (u.x + u.y) + (u.z + u.w);
    }
    float sum = block_sum(psum, red, 0);

#pragma unroll
    for (int it = 0; it < 10; ++it) {
        float mean = sum * (1.0f / 8192.0f);  // exact pow-2: identical to /8192
        float add = (it == 0) ? 0.001f : 0.0f;
        psum = 0.0f;
#pragma unroll
        for (int k = 0; k < 8; ++k) {
            float4 u = a[k];
            u.x = u.x * (1.0f - (u.x - mean)) + add;
            u.y = u.y * (1.0f - (u.y - mean)) + add;
            u.z = u.z * (1.0f - (u.z - mean)) + add;
            u.w = u.w * (1.0f - (u.w - mean)) + add;
            a[k] = u;
            psum += (u.x + u.y) + (u.z + u.w);
        }
        if (it < 9) sum = block_sum(psum, red, (it + 1) & 1);  // uniform: barrier-safe
    }

#pragma unroll
    for (int k = 0; k < 8; ++k) {
        int c = k * 1024 + t * 4;
        float4 mn = *(const float4*)(fmin + c);
        float4 sr = *(const float4*)(fsr + c);
        float4 u = a[k];
        float* o = outr + c;
        __builtin_nontemporal_store(fmaf(u.x, sr.x, mn.x), o + 0);
        __builtin_nontemporal_store(fmaf(u.y, sr.y, mn.y), o + 1);
        __builtin_nontemporal_store(fmaf(u.z, sr.z, mn.z), o + 2);
        __builtin_nontemporal_store(fmaf(u.w, sr.w, mn.w), o + 3);
    }
}

extern "C" void kernel_launch(void* const* d_in, const int* in_sizes, int n_in,
                              void* d_out, int out_size, void* d_ws, size_t ws_size,
                              hipStream_t stream) {
    const float* x = (const float*)d_in[0];
    float* out = (float*)d_out;

    // ws layout: mine[8192] u32 (-> fsr f32) | maxe[8192] u32 (-> finv f32) |
    //            fmin[8192] f32  = 96 KiB total
    unsigned* mine = (unsigned*)d_ws;
    unsigned* maxe = mine + NCOLS;
    float* fmin = (float*)(maxe + NCOLS);

    hipMemsetAsync(mine, 0xFF, NCOLS * sizeof(unsigned), stream);  // encoded-min identity
    hipMemsetAsync(maxe, 0x00, NCOLS * sizeof(unsigned), stream);  // encoded-max identity
    colminmax<<<dim3(NCOLS / 1024, DROWS / 64), 256, 0, stream>>>(x, mine, maxe);
    finalize_minmax<<<NCOLS / 256, 256, 0, stream>>>(mine, maxe, fmin);
    rowiter<<<DROWS, 256, 0, stream>>>(x, fmin, (const float*)mine,
                                       (const float*)maxe, out);
}

// Round 10
// 74.466 us; speedup vs baseline: 2.0554x; 1.1849x over previous
//
#include <hip/hip_runtime.h>

#define DROWS 4096
#define NCOLS 8192
#define RTILE 64                 // rows per colminmax tile
#define NTILES (DROWS / RTILE)   // 64 partial tiles

// ===================== primary path: two-level min/max =====================

// Per-column partial min/max over a 64-row tile. grid (8, 64); block 256 thr,
// 4 cols/thread, coalesced float4. No atomics, no init required.
__global__ __launch_bounds__(256) void colminmax_part(const float* __restrict__ x,
                                                      float* __restrict__ pmin,
                                                      float* __restrict__ pmax) {
    int c = blockIdx.x * 1024 + threadIdx.x * 4;
    int r0 = blockIdx.y * RTILE;
    const float* p = x + (size_t)r0 * NCOLS + c;

    float4 mn = *(const float4*)p;
    float4 mx = mn;
#pragma unroll 8
    for (int i = 1; i < RTILE; ++i) {
        float4 v = *(const float4*)(p + (size_t)i * NCOLS);
        mn.x = fminf(mn.x, v.x); mn.y = fminf(mn.y, v.y);
        mn.z = fminf(mn.z, v.z); mn.w = fminf(mn.w, v.w);
        mx.x = fmaxf(mx.x, v.x); mx.y = fmaxf(mx.y, v.y);
        mx.z = fmaxf(mx.z, v.z); mx.w = fmaxf(mx.w, v.w);
    }
    size_t o = (size_t)blockIdx.y * NCOLS + c;
    *(float4*)(pmin + o) = mn;
    *(float4*)(pmax + o) = mx;
}

// Reduce 64 partials per column; emit fmin, safe_range, 1/safe_range.
// Lane i handles col b*256+i: per y the wave reads 64 consecutive floats.
__global__ __launch_bounds__(256) void finalize_part(const float* __restrict__ pmin,
                                                     const float* __restrict__ pmax,
                                                     float* __restrict__ fmin,
                                                     float* __restrict__ fsr,
                                                     float* __restrict__ finv) {
    int col = blockIdx.x * 256 + threadIdx.x;
    float mn = pmin[col];
    float mx = pmax[col];
#pragma unroll 9
    for (int y = 1; y < NTILES; ++y) {
        mn = fminf(mn, pmin[(size_t)y * NCOLS + col]);
        mx = fmaxf(mx, pmax[(size_t)y * NCOLS + col]);
    }
    float r = mx - mn;
    float sr = (r == 0.0f) ? 1.0f : r;  // sklearn _handle_zeros_in_scale
    fmin[col] = mn;
    fsr[col] = sr;
    finv[col] = 1.0f / sr;
}

// ===================== fallback path (ws too small): atomics ==============

__device__ __forceinline__ unsigned encf(float f) {
    unsigned u = __float_as_uint(f);
    return (u & 0x80000000u) ? ~u : (u | 0x80000000u);
}
__device__ __forceinline__ float decf(unsigned u) {
    unsigned v = (u & 0x80000000u) ? (u ^ 0x80000000u) : ~u;
    return __uint_as_float(v);
}

__global__ __launch_bounds__(256) void colminmax_atomic(const float* __restrict__ x,
                                                        unsigned* __restrict__ mine,
                                                        unsigned* __restrict__ maxe) {
    int c = blockIdx.x * 1024 + threadIdx.x * 4;
    int r0 = blockIdx.y * RTILE;
    const float* p = x + (size_t)r0 * NCOLS + c;
    float4 mn = *(const float4*)p;
    float4 mx = mn;
#pragma unroll 8
    for (int i = 1; i < RTILE; ++i) {
        float4 v = *(const float4*)(p + (size_t)i * NCOLS);
        mn.x = fminf(mn.x, v.x); mn.y = fminf(mn.y, v.y);
        mn.z = fminf(mn.z, v.z); mn.w = fminf(mn.w, v.w);
        mx.x = fmaxf(mx.x, v.x); mx.y = fmaxf(mx.y, v.y);
        mx.z = fmaxf(mx.z, v.z); mx.w = fmaxf(mx.w, v.w);
    }
    atomicMin(&mine[c + 0], encf(mn.x)); atomicMin(&mine[c + 1], encf(mn.y));
    atomicMin(&mine[c + 2], encf(mn.z)); atomicMin(&mine[c + 3], encf(mn.w));
    atomicMax(&maxe[c + 0], encf(mx.x)); atomicMax(&maxe[c + 1], encf(mx.y));
    atomicMax(&maxe[c + 2], encf(mx.z)); atomicMax(&maxe[c + 3], encf(mx.w));
}

__global__ __launch_bounds__(256) void finalize_atomic(unsigned* __restrict__ mine,
                                                       unsigned* __restrict__ maxe,
                                                       float* __restrict__ fmin) {
    int i = blockIdx.x * 256 + threadIdx.x;
    float mn = decf(mine[i]);
    float mx = decf(maxe[i]);
    float r = mx - mn;
    float sr = (r == 0.0f) ? 1.0f : r;
    fmin[i] = mn;
    ((float*)mine)[i] = sr;       // fsr
    ((float*)maxe)[i] = 1.0f / sr;  // finv
}

// ===================== rowiter ============================================

// One-barrier block sum: double-buffered slots; consecutive calls alternate
// slot, so a slot's next writer is separated from its readers by a barrier.
__device__ __forceinline__ float block_sum(float v, float* red, int slot) {
#pragma unroll
    for (int m = 32; m; m >>= 1) v += __shfl_xor(v, m, 64);
    int wid = threadIdx.x >> 6;
    int lane = threadIdx.x & 63;
    if (lane == 0) red[slot * 4 + wid] = v;
    __syncthreads();
    float* r = red + slot * 4;
    return r[0] + r[1] + r[2] + r[3];
}

// One block per row; 8 x float4/thread in registers. Inner loop folded to
// 3 VALU/elem: t=c1-u; u=fma(u,t,add); psum+=u  (c1=1+mean hoisted).
// Final iteration fused with the NT-store epilogue (no psum, no reduce).
__global__ __launch_bounds__(256, 6) void rowiter(const float* __restrict__ x,
                                                  const float* __restrict__ fmin,
                                                  const float* __restrict__ fsr,
                                                  const float* __restrict__ finv,
                                                  float* __restrict__ out) {
    int row = blockIdx.x;
    int t = threadIdx.x;
    const float* xr = x + (size_t)row * NCOLS;
    float* outr = out + (size_t)row * NCOLS;

    __shared__ float red[8];

    float4 a[8];
    float psum = 0.0f;
#pragma unroll
    for (int k = 0; k < 8; ++k) {
        int c = k * 1024 + t * 4;
        float4 v = *(const float4*)(xr + c);
        float4 mn = *(const float4*)(fmin + c);
        float4 iv = *(const float4*)(finv + c);
        float4 u;
        u.x = (v.x - mn.x) * iv.x;
        u.y = (v.y - mn.y) * iv.y;
        u.z = (v.z - mn.z) * iv.z;
        u.w = (v.w - mn.w) * iv.w;
        a[k] = u;
        psum += (u.x + u.y) + (u.z + u.w);
    }
    float sum = block_sum(psum, red, 0);

    // iterations 0..8 (iteration 9 fused below)
#pragma unroll
    for (int it = 0; it < 9; ++it) {
        float c1 = 1.0f + sum * (1.0f / 8192.0f);  // 1 + mean
        float add = (it == 0) ? 0.001f : 0.0f;
        psum = 0.0f;
#pragma unroll
        for (int k = 0; k < 8; ++k) {
            float4 u = a[k];
            u.x = fmaf(u.x, c1 - u.x, add);
            u.y = fmaf(u.y, c1 - u.y, add);
            u.z = fmaf(u.z, c1 - u.z, add);
            u.w = fmaf(u.w, c1 - u.w, add);
            a[k] = u;
            psum += (u.x + u.y) + (u.z + u.w);
        }
        sum = block_sum(psum, red, (it + 1) & 1);
    }

    // iteration 9 fused with denormalize + non-temporal store
    {
        float c1 = 1.0f + sum * (1.0f / 8192.0f);
#pragma unroll
        for (int k = 0; k < 8; ++k) {
            int c = k * 1024 + t * 4;
            float4 mn = *(const float4*)(fmin + c);
            float4 sr = *(const float4*)(fsr + c);
            float4 u = a[k];
            u.x = u.x * (c1 - u.x);
            u.y = u.y * (c1 - u.y);
            u.z = u.z * (c1 - u.z);
            u.w = u.w * (c1 - u.w);
            float* o = outr + c;
            __builtin_nontemporal_store(fmaf(u.x, sr.x, mn.x), o + 0);
            __builtin_nontemporal_store(fmaf(u.y, sr.y, mn.y), o + 1);
            __builtin_nontemporal_store(fmaf(u.z, sr.z, mn.z), o + 2);
            __builtin_nontemporal_store(fmaf(u.w, sr.w, mn.w), o + 3);
        }
    }
}

extern "C" void kernel_launch(void* const* d_in, const int* in_sizes, int n_in,
                              void* d_out, int out_size, void* d_ws, size_t ws_size,
                              hipStream_t stream) {
    const float* x = (const float*)d_in[0];
    float* out = (float*)d_out;

    // primary ws layout: pmin[64][8192] f32 (2 MiB) | pmax (2 MiB) |
    //                    fmin | fsr | finv (32 KiB each)  = 4.09 MiB
    size_t need = (size_t)NTILES * NCOLS * 2 * sizeof(float) + 3 * NCOLS * sizeof(float);

    if (ws_size >= need) {
        float* pmin = (float*)d_ws;
        float* pmax = pmin + (size_t)NTILES * NCOLS;
        float* fmin = pmax + (size_t)NTILES * NCOLS;
        float* fsr = fmin + NCOLS;
        float* finv = fsr + NCOLS;

        colminmax_part<<<dim3(NCOLS / 1024, NTILES), 256, 0, stream>>>(x, pmin, pmax);
        finalize_part<<<NCOLS / 256, 256, 0, stream>>>(pmin, pmax, fmin, fsr, finv);
        rowiter<<<DROWS, 256, 0, stream>>>(x, fmin, fsr, finv, out);
    } else {
        // fallback: atomic path (96 KiB ws)
        unsigned* mine = (unsigned*)d_ws;
        unsigned* maxe = mine + NCOLS;
        float* fmin = (float*)(maxe + NCOLS);

        hipMemsetAsync(mine, 0xFF, NCOLS * sizeof(unsigned), stream);
        hipMemsetAsync(maxe, 0x00, NCOLS * sizeof(unsigned), stream);
        colminmax_atomic<<<dim3(NCOLS / 1024, NTILES), 256, 0, stream>>>(x, mine, maxe);
        finalize_atomic<<<NCOLS / 256, 256, 0, stream>>>(mine, maxe, fmin);
        rowiter<<<DROWS, 256, 0, stream>>>(x, fmin, (const float*)mine,
                                           (const float*)maxe, out);
    }
}